// Round 1
// baseline (1121.453 us; speedup 1.0000x reference)
//
#include <hip/hip_runtime.h>
#include <stdint.h>

// Problem constants (B=4, S=2048 -> T=8192 tokens)
#define T_TOK 8192
#define DIM   1024
#define NEXP  8
#define HID   2816

typedef __bf16 bf16x8 __attribute__((ext_vector_type(8)));
typedef float  f32x4  __attribute__((ext_vector_type(4)));

__device__ __forceinline__ uint32_t f2bf_u(float f) {
    uint32_t u = __builtin_bit_cast(uint32_t, f);
    return u + 0x7fffu + ((u >> 16) & 1u);   // RNE to bf16, top 16 bits valid
}
__device__ __forceinline__ uint32_t pack2(float a, float b) {
    return (f2bf_u(a) >> 16) | (f2bf_u(b) & 0xffff0000u);
}
__device__ __forceinline__ void cvt16_pack(const float4* s4, uint4& o0, uint4& o1) {
    float4 a = s4[0], b = s4[1], c = s4[2], d = s4[3];
    o0.x = pack2(a.x, a.y); o0.y = pack2(a.z, a.w);
    o0.z = pack2(b.x, b.y); o0.w = pack2(b.z, b.w);
    o1.x = pack2(c.x, c.y); o1.y = pack2(c.z, c.w);
    o1.z = pack2(d.x, d.y); o1.w = pack2(d.z, d.w);
}

// ---------------------------------------------------------------------------
// Kernel 1: router. One wave per token. fp64-accumulated logits (stability of
// top-2 selection vs np reference), top-2 + softmax, build per-expert gather
// lists with atomic counters.
// ---------------------------------------------------------------------------
__global__ __launch_bounds__(256) void router_k(
    const float* __restrict__ x, const float* __restrict__ gw,
    int* __restrict__ cnt, int* __restrict__ slot_list,
    float* __restrict__ slot_w)
{
    const int wave = threadIdx.x >> 6, lane = threadIdx.x & 63;
    const int t = blockIdx.x * 4 + wave;
    const float4* xp = (const float4*)(x + (size_t)t * DIM + lane * 16);
    float4 xv[4];
#pragma unroll
    for (int i = 0; i < 4; ++i) xv[i] = xp[i];

    double lg[NEXP];
#pragma unroll
    for (int e = 0; e < NEXP; ++e) {
        const float4* gp = (const float4*)(gw + (size_t)e * DIM + lane * 16);
        double s = 0.0;
#pragma unroll
        for (int i = 0; i < 4; ++i) {
            float4 g = gp[i];
            s += (double)xv[i].x * g.x + (double)xv[i].y * g.y +
                 (double)xv[i].z * g.z + (double)xv[i].w * g.w;
        }
#pragma unroll
        for (int m = 32; m >= 1; m >>= 1) s += __shfl_xor(s, m, 64);
        lg[e] = s;
    }

    if (lane == 0) {
        int e0 = 0; double b0 = lg[0];
#pragma unroll
        for (int e = 1; e < NEXP; ++e)
            if (lg[e] > b0) { b0 = lg[e]; e0 = e; }
        int e1 = -1; double b1 = -1.0e300;
#pragma unroll
        for (int e = 0; e < NEXP; ++e)
            if (e != e0 && lg[e] > b1) { b1 = lg[e]; e1 = e; }

        float p0 = (float)(1.0 / (1.0 + exp(b1 - b0)));
        float p1 = 1.0f - p0;

        int pos0 = atomicAdd(&cnt[e0], 1);
        slot_list[e0 * T_TOK + pos0] = 2 * t;
        slot_w[2 * t] = p0;
        int pos1 = atomicAdd(&cnt[e1], 1);
        slot_list[e1 * T_TOK + pos1] = 2 * t + 1;
        slot_w[2 * t + 1] = p1;
    }
}

// ---------------------------------------------------------------------------
// Kernel 2: per-expert gathered GEMM, fused w1/w3 + SwiGLU.
// C-tile: 128 slots x 64 hid (per matrix). 4 waves, each 64x32 per matrix,
// 16x16x32 bf16 MFMA. fp32 -> bf16 conversion in staging.
// grid: (HID/64 = 44, T/128 = 64, NEXP = 8), early-exit on m0 >= cnt[e].
// ---------------------------------------------------------------------------
__global__ __launch_bounds__(256) void ffn1_k(
    const float* __restrict__ x, const float* __restrict__ w1,
    const float* __restrict__ w3, const int* __restrict__ cnt,
    const int* __restrict__ slot_list, unsigned short* __restrict__ h_ws)
{
    __shared__ unsigned short As[128 * 32];
    __shared__ unsigned short B1s[64 * 32];
    __shared__ unsigned short B2s[64 * 32];
    __shared__ int slots_s[128];

    const int e = blockIdx.z;
    const int cntE = cnt[e];
    const int m0 = blockIdx.y * 128;
    if (m0 >= cntE) return;
    const int n0 = blockIdx.x * 64;
    const int tid = threadIdx.x;

    if (tid < 128) {
        int idx = m0 + tid;
        slots_s[tid] = (idx < cntE) ? slot_list[e * T_TOK + idx] : -1;
    }
    __syncthreads();

    const float* w1e = w1 + (size_t)e * HID * DIM;
    const float* w3e = w3 + (size_t)e * HID * DIM;

    // staging roles
    const int arow = tid >> 1, ahalf = tid & 1;          // A: 128 rows x 2 halves
    const int brow = (tid >> 1) & 63, bmat = tid >> 7;   // B: 2 mats x 64 rows x 2 halves
    const int aslot = slots_s[arow];
    const float* asrc = (aslot >= 0)
        ? (x + (size_t)(aslot >> 1) * DIM + ahalf * 16) : (const float*)0;
    const float* bsrc = (bmat ? w3e : w1e) + (size_t)(n0 + brow) * DIM + (tid & 1) * 16;
    unsigned short* adst = &As[arow * 32 + ahalf * 16];
    unsigned short* bdst = (bmat ? B2s : B1s) + (brow * 32 + (tid & 1) * 16);

    // mfma roles
    const int wave = tid >> 6, lane = tid & 63;
    const int wm = wave >> 1, wn = wave & 1;
    const int lrow = lane & 15, koff = (lane >> 4) * 8, quad = lane >> 4;

    f32x4 acc1[4][2], acc2[4][2];
    const f32x4 zf = {0.f, 0.f, 0.f, 0.f};
#pragma unroll
    for (int mi = 0; mi < 4; ++mi)
#pragma unroll
        for (int ni = 0; ni < 2; ++ni) { acc1[mi][ni] = zf; acc2[mi][ni] = zf; }

    for (int k0 = 0; k0 < DIM; k0 += 32) {
        uint4 av0, av1, bv0, bv1;
        if (aslot >= 0) {
            cvt16_pack((const float4*)(asrc + k0), av0, av1);
        } else {
            av0 = make_uint4(0, 0, 0, 0); av1 = make_uint4(0, 0, 0, 0);
        }
        cvt16_pack((const float4*)(bsrc + k0), bv0, bv1);

        ((uint4*)adst)[0] = av0; ((uint4*)adst)[1] = av1;
        ((uint4*)bdst)[0] = bv0; ((uint4*)bdst)[1] = bv1;
        __syncthreads();

        bf16x8 af[4], b1f[2], b2f[2];
#pragma unroll
        for (int mi = 0; mi < 4; ++mi)
            af[mi] = *(const bf16x8*)&As[(wm * 64 + mi * 16 + lrow) * 32 + koff];
#pragma unroll
        for (int ni = 0; ni < 2; ++ni) {
            b1f[ni] = *(const bf16x8*)&B1s[(wn * 32 + ni * 16 + lrow) * 32 + koff];
            b2f[ni] = *(const bf16x8*)&B2s[(wn * 32 + ni * 16 + lrow) * 32 + koff];
        }
#pragma unroll
        for (int mi = 0; mi < 4; ++mi)
#pragma unroll
            for (int ni = 0; ni < 2; ++ni) {
                acc1[mi][ni] = __builtin_amdgcn_mfma_f32_16x16x32_bf16(
                    af[mi], b1f[ni], acc1[mi][ni], 0, 0, 0);
                acc2[mi][ni] = __builtin_amdgcn_mfma_f32_16x16x32_bf16(
                    af[mi], b2f[ni], acc2[mi][ni], 0, 0, 0);
            }
        __syncthreads();
    }

    // epilogue: h = silu(a1) * a3, bf16 store to h_ws[slot, n]
#pragma unroll
    for (int mi = 0; mi < 4; ++mi) {
#pragma unroll
        for (int r = 0; r < 4; ++r) {
            int mloc = wm * 64 + mi * 16 + quad * 4 + r;
            int slot = slots_s[mloc];
            if (slot >= 0) {
                unsigned short* hrow =
                    h_ws + (size_t)slot * HID + n0 + wn * 32 + lrow;
#pragma unroll
                for (int ni = 0; ni < 2; ++ni) {
                    float a1 = acc1[mi][ni][r], a3 = acc2[mi][ni][r];
                    float hv = (a1 / (1.f + __expf(-a1))) * a3;
                    hrow[ni * 16] = (unsigned short)(f2bf_u(hv) >> 16);
                }
            }
        }
    }
}

// ---------------------------------------------------------------------------
// Kernel 3: per-expert gathered GEMM y = h @ w2^T, scale by routing weight,
// atomicAdd into out. C-tile 128 x 128, 4 waves each 64x64.
// grid: (DIM/128 = 8, T/128 = 64, NEXP = 8)
// ---------------------------------------------------------------------------
__global__ __launch_bounds__(256) void ffn2_k(
    const unsigned short* __restrict__ h_ws, const float* __restrict__ w2,
    const int* __restrict__ cnt, const int* __restrict__ slot_list,
    const float* __restrict__ slot_w, float* __restrict__ out)
{
    __shared__ unsigned short As[128 * 32];
    __shared__ unsigned short Bs[128 * 32];
    __shared__ int slots_s[128];
    __shared__ float wgt_s[128];

    const int e = blockIdx.z;
    const int cntE = cnt[e];
    const int m0 = blockIdx.y * 128;
    if (m0 >= cntE) return;
    const int n0 = blockIdx.x * 128;
    const int tid = threadIdx.x;

    if (tid < 128) {
        int idx = m0 + tid;
        int s = (idx < cntE) ? slot_list[e * T_TOK + idx] : -1;
        slots_s[tid] = s;
        wgt_s[tid] = (s >= 0) ? slot_w[s] : 0.f;
    }
    __syncthreads();

    const float* w2e = w2 + (size_t)e * DIM * HID;

    const int row = tid >> 1, half = tid & 1;
    const int aslot = slots_s[row];
    const unsigned short* asrc = (aslot >= 0)
        ? (h_ws + (size_t)aslot * HID + half * 16) : (const unsigned short*)0;
    const float* bsrc = w2e + (size_t)(n0 + row) * HID + half * 16;
    unsigned short* adst = &As[row * 32 + half * 16];
    unsigned short* bdst = &Bs[row * 32 + half * 16];

    const int wave = tid >> 6, lane = tid & 63;
    const int wm = wave >> 1, wn = wave & 1;
    const int lrow = lane & 15, koff = (lane >> 4) * 8, quad = lane >> 4;

    f32x4 acc[4][4];
    const f32x4 zf = {0.f, 0.f, 0.f, 0.f};
#pragma unroll
    for (int mi = 0; mi < 4; ++mi)
#pragma unroll
        for (int ni = 0; ni < 4; ++ni) acc[mi][ni] = zf;

    for (int k0 = 0; k0 < HID; k0 += 32) {
        uint4 av0, av1, bv0, bv1;
        if (aslot >= 0) {
            const uint4* s4 = (const uint4*)(asrc + k0);
            av0 = s4[0]; av1 = s4[1];
        } else {
            av0 = make_uint4(0, 0, 0, 0); av1 = make_uint4(0, 0, 0, 0);
        }
        cvt16_pack((const float4*)(bsrc + k0), bv0, bv1);

        ((uint4*)adst)[0] = av0; ((uint4*)adst)[1] = av1;
        ((uint4*)bdst)[0] = bv0; ((uint4*)bdst)[1] = bv1;
        __syncthreads();

        bf16x8 af[4], bf[4];
#pragma unroll
        for (int mi = 0; mi < 4; ++mi)
            af[mi] = *(const bf16x8*)&As[(wm * 64 + mi * 16 + lrow) * 32 + koff];
#pragma unroll
        for (int ni = 0; ni < 4; ++ni)
            bf[ni] = *(const bf16x8*)&Bs[(wn * 64 + ni * 16 + lrow) * 32 + koff];
#pragma unroll
        for (int mi = 0; mi < 4; ++mi)
#pragma unroll
            for (int ni = 0; ni < 4; ++ni)
                acc[mi][ni] = __builtin_amdgcn_mfma_f32_16x16x32_bf16(
                    af[mi], bf[ni], acc[mi][ni], 0, 0, 0);
        __syncthreads();
    }

#pragma unroll
    for (int mi = 0; mi < 4; ++mi) {
#pragma unroll
        for (int r = 0; r < 4; ++r) {
            int mloc = wm * 64 + mi * 16 + quad * 4 + r;
            int slot = slots_s[mloc];
            if (slot >= 0) {
                int tok = slot >> 1;
                float w = wgt_s[mloc];
                float* orow = out + (size_t)tok * DIM + n0 + wn * 64 + lrow;
#pragma unroll
                for (int ni = 0; ni < 4; ++ni)
                    atomicAdd(&orow[ni * 16], acc[mi][ni][r] * w);
            }
        }
    }
}

// ---------------------------------------------------------------------------
// Workspace layout:
//   [0,256)                      : cnt[8] (zeroed each launch)
//   [256, 256+262144)            : slot_list[8][8192]
//   [+262144, +65536)            : slot_w[16384]
//   [327936, +92274688)          : h_ws bf16 [16384][2816]   (~88 MB)
// ---------------------------------------------------------------------------
extern "C" void kernel_launch(void* const* d_in, const int* in_sizes, int n_in,
                              void* d_out, int out_size, void* d_ws, size_t ws_size,
                              hipStream_t stream) {
    const float* x  = (const float*)d_in[0];
    const float* gw = (const float*)d_in[1];
    const float* w1 = (const float*)d_in[2];
    const float* w2 = (const float*)d_in[3];
    const float* w3 = (const float*)d_in[4];
    float* out = (float*)d_out;

    char* ws = (char*)d_ws;
    int*   cnt       = (int*)ws;
    int*   slot_list = (int*)(ws + 256);
    float* slot_w    = (float*)(ws + 256 + NEXP * T_TOK * 4);
    unsigned short* h_ws =
        (unsigned short*)(ws + 256 + NEXP * T_TOK * 4 + 2 * T_TOK * 4);

    hipMemsetAsync(cnt, 0, 256, stream);
    hipMemsetAsync(out, 0, (size_t)T_TOK * DIM * sizeof(float), stream);

    router_k<<<T_TOK / 4, 256, 0, stream>>>(x, gw, cnt, slot_list, slot_w);
    ffn1_k<<<dim3(HID / 64, T_TOK / 128, NEXP), 256, 0, stream>>>(
        x, w1, w3, cnt, slot_list, h_ws);
    ffn2_k<<<dim3(DIM / 128, T_TOK / 128, NEXP), 256, 0, stream>>>(
        h_ws, w2, cnt, slot_list, slot_w, out);
}

// Round 2
// 939.718 us; speedup vs baseline: 1.1934x; 1.1934x over previous
//
#include <hip/hip_runtime.h>
#include <stdint.h>

// Problem constants (B=4, S=2048 -> T=8192 tokens)
#define T_TOK 8192
#define DIM   1024
#define NEXP  8
#define HID   2816

typedef __bf16 bf16x8 __attribute__((ext_vector_type(8)));
typedef float  f32x4  __attribute__((ext_vector_type(4)));

typedef __attribute__((address_space(3))) uint32_t lds_u32_t;
typedef __attribute__((address_space(1))) const uint32_t gbl_u32_t;

// async global->LDS, 16B per lane. LDS dest = wave-uniform base + lane*16.
__device__ __forceinline__ void gl_lds16(const void* g, void* l) {
    __builtin_amdgcn_global_load_lds((gbl_u32_t*)g, (lds_u32_t*)l, 16, 0, 0);
}

__device__ __forceinline__ uint32_t f2bf_u(float f) {
    uint32_t u = __builtin_bit_cast(uint32_t, f);
    return u + 0x7fffu + ((u >> 16) & 1u);   // RNE to bf16, top 16 bits valid
}
__device__ __forceinline__ uint32_t pack2(float a, float b) {
    return (f2bf_u(a) >> 16) | (f2bf_u(b) & 0xffff0000u);
}

// ---------------------------------------------------------------------------
// Kernel 0: fp32 -> bf16 conversion (weights + x), 8 floats/thread.
// ---------------------------------------------------------------------------
__global__ __launch_bounds__(256) void cvt_k(
    const float* __restrict__ s, unsigned short* __restrict__ d, int n8)
{
    int i = blockIdx.x * 256 + threadIdx.x;
    if (i < n8) {
        const float4* sp = (const float4*)(s + (size_t)i * 8);
        float4 a = sp[0], b = sp[1];
        uint4 o;
        o.x = pack2(a.x, a.y); o.y = pack2(a.z, a.w);
        o.z = pack2(b.x, b.y); o.w = pack2(b.z, b.w);
        ((uint4*)d)[i] = o;
    }
}

// ---------------------------------------------------------------------------
// Kernel 1: router. One wave per token, fp64 logits, top-2 + softmax,
// per-expert gather lists via atomic counters.
// ---------------------------------------------------------------------------
__global__ __launch_bounds__(256) void router_k(
    const float* __restrict__ x, const float* __restrict__ gw,
    int* __restrict__ cnt, int* __restrict__ slot_list,
    float* __restrict__ slot_w)
{
    const int wave = threadIdx.x >> 6, lane = threadIdx.x & 63;
    const int t = blockIdx.x * 4 + wave;
    const float4* xp = (const float4*)(x + (size_t)t * DIM + lane * 16);
    float4 xv[4];
#pragma unroll
    for (int i = 0; i < 4; ++i) xv[i] = xp[i];

    double lg[NEXP];
#pragma unroll
    for (int e = 0; e < NEXP; ++e) {
        const float4* gp = (const float4*)(gw + (size_t)e * DIM + lane * 16);
        double s = 0.0;
#pragma unroll
        for (int i = 0; i < 4; ++i) {
            float4 g = gp[i];
            s += (double)xv[i].x * g.x + (double)xv[i].y * g.y +
                 (double)xv[i].z * g.z + (double)xv[i].w * g.w;
        }
#pragma unroll
        for (int m = 32; m >= 1; m >>= 1) s += __shfl_xor(s, m, 64);
        lg[e] = s;
    }

    if (lane == 0) {
        int e0 = 0; double b0 = lg[0];
#pragma unroll
        for (int e = 1; e < NEXP; ++e)
            if (lg[e] > b0) { b0 = lg[e]; e0 = e; }
        int e1 = -1; double b1 = -1.0e300;
#pragma unroll
        for (int e = 0; e < NEXP; ++e)
            if (e != e0 && lg[e] > b1) { b1 = lg[e]; e1 = e; }

        float p0 = (float)(1.0 / (1.0 + exp(b1 - b0)));
        float p1 = 1.0f - p0;

        int pos0 = atomicAdd(&cnt[e0], 1);
        slot_list[e0 * T_TOK + pos0] = 2 * t;
        slot_w[2 * t] = p0;
        int pos1 = atomicAdd(&cnt[e1], 1);
        slot_list[e1 * T_TOK + pos1] = 2 * t + 1;
        slot_w[2 * t + 1] = p1;
    }
}

// ---------------------------------------------------------------------------
// Kernel 2: gathered GEMM, fused w1/w3 + SwiGLU. All-bf16 inputs, staged via
// global_load_lds dwordx4. C-tile 128 slots x (64+64) hid.
// grid (HID/64=44, ceilT/128, NEXP), early-exit on empty m-block.
// ---------------------------------------------------------------------------
__global__ __launch_bounds__(256) void ffn1_k(
    const unsigned short* __restrict__ xb, const unsigned short* __restrict__ w1b,
    const unsigned short* __restrict__ w3b, const int* __restrict__ cnt,
    const int* __restrict__ slot_list, unsigned short* __restrict__ h_ws)
{
    __shared__ unsigned short As[128 * 32];
    __shared__ unsigned short B1s[64 * 32];
    __shared__ unsigned short B2s[64 * 32];
    __shared__ int slots_s[128];

    const int e = blockIdx.z;
    const int cntE = cnt[e];
    const int m0 = blockIdx.y * 128;
    if (m0 >= cntE) return;
    const int n0 = blockIdx.x * 64;
    const int tid = threadIdx.x;
    const int wave = tid >> 6, lane = tid & 63;

    if (tid < 128) {
        int idx = m0 + tid;
        slots_s[tid] = (idx < cntE) ? slot_list[e * T_TOK + idx] : -1;
    }
    __syncthreads();

    // staging: 4 global_load_lds per wave per k-step.
    // waves 0,1 -> A rows (gathered tokens); wave 2 -> w1 rows; wave 3 -> w3 rows.
    const int sub = lane >> 2;   // row within 16-row instruction
    const int kq  = lane & 3;    // 16B quarter within 64B row
    const unsigned short* gsrc[4];
    unsigned short* ldst[4];
    if (wave < 2) {
#pragma unroll
        for (int i = 0; i < 4; ++i) {
            int row = wave * 64 + i * 16 + sub;
            int slot = slots_s[row];
            int tok = (slot >= 0) ? (slot >> 1) : 0;   // clamp tail to token 0
            gsrc[i] = xb + (size_t)tok * DIM + kq * 8;
            ldst[i] = &As[(wave * 64 + i * 16) * 32];
        }
    } else if (wave == 2) {
#pragma unroll
        for (int i = 0; i < 4; ++i) {
            int row = i * 16 + sub;
            gsrc[i] = w1b + ((size_t)e * HID + n0 + row) * DIM + kq * 8;
            ldst[i] = &B1s[(i * 16) * 32];
        }
    } else {
#pragma unroll
        for (int i = 0; i < 4; ++i) {
            int row = i * 16 + sub;
            gsrc[i] = w3b + ((size_t)e * HID + n0 + row) * DIM + kq * 8;
            ldst[i] = &B2s[(i * 16) * 32];
        }
    }

    const int wm = wave >> 1, wn = wave & 1;
    const int lrow = lane & 15, koff = (lane >> 4) * 8, quad = lane >> 4;

    f32x4 acc1[4][2], acc2[4][2];
    const f32x4 zf = {0.f, 0.f, 0.f, 0.f};
#pragma unroll
    for (int mi = 0; mi < 4; ++mi)
#pragma unroll
        for (int ni = 0; ni < 2; ++ni) { acc1[mi][ni] = zf; acc2[mi][ni] = zf; }

    for (int k0 = 0; k0 < DIM; k0 += 32) {
#pragma unroll
        for (int i = 0; i < 4; ++i) gl_lds16(gsrc[i], ldst[i]);
#pragma unroll
        for (int i = 0; i < 4; ++i) gsrc[i] += 32;
        __syncthreads();

        bf16x8 af[4], b1f[2], b2f[2];
#pragma unroll
        for (int mi = 0; mi < 4; ++mi)
            af[mi] = *(const bf16x8*)&As[(wm * 64 + mi * 16 + lrow) * 32 + koff];
#pragma unroll
        for (int ni = 0; ni < 2; ++ni) {
            b1f[ni] = *(const bf16x8*)&B1s[(wn * 32 + ni * 16 + lrow) * 32 + koff];
            b2f[ni] = *(const bf16x8*)&B2s[(wn * 32 + ni * 16 + lrow) * 32 + koff];
        }
#pragma unroll
        for (int mi = 0; mi < 4; ++mi)
#pragma unroll
            for (int ni = 0; ni < 2; ++ni) {
                acc1[mi][ni] = __builtin_amdgcn_mfma_f32_16x16x32_bf16(
                    af[mi], b1f[ni], acc1[mi][ni], 0, 0, 0);
                acc2[mi][ni] = __builtin_amdgcn_mfma_f32_16x16x32_bf16(
                    af[mi], b2f[ni], acc2[mi][ni], 0, 0, 0);
            }
        __syncthreads();
    }

    // epilogue: h = silu(a1) * a3 -> bf16 h_ws[slot, n]
#pragma unroll
    for (int mi = 0; mi < 4; ++mi) {
#pragma unroll
        for (int r = 0; r < 4; ++r) {
            int mloc = wm * 64 + mi * 16 + quad * 4 + r;
            int slot = slots_s[mloc];
            if (slot >= 0) {
                unsigned short* hrow =
                    h_ws + (size_t)slot * HID + n0 + wn * 32 + lrow;
#pragma unroll
                for (int ni = 0; ni < 2; ++ni) {
                    float a1 = acc1[mi][ni][r], a3 = acc2[mi][ni][r];
                    float hv = (a1 / (1.f + __expf(-a1))) * a3;
                    hrow[ni * 16] = (unsigned short)(f2bf_u(hv) >> 16);
                }
            }
        }
    }
}

// ---------------------------------------------------------------------------
// Kernel 3: gathered GEMM y = h @ w2^T, scale by routing weight, atomicAdd
// into out. C-tile 128 x 128. grid (DIM/128=8, ceilT/128, NEXP).
// ---------------------------------------------------------------------------
__global__ __launch_bounds__(256) void ffn2_k(
    const unsigned short* __restrict__ h_ws, const unsigned short* __restrict__ w2b,
    const int* __restrict__ cnt, const int* __restrict__ slot_list,
    const float* __restrict__ slot_w, float* __restrict__ out)
{
    __shared__ unsigned short As[128 * 32];
    __shared__ unsigned short Bs[128 * 32];
    __shared__ int slots_s[128];
    __shared__ float wgt_s[128];

    const int e = blockIdx.z;
    const int cntE = cnt[e];
    const int m0 = blockIdx.y * 128;
    if (m0 >= cntE) return;
    const int n0 = blockIdx.x * 128;
    const int tid = threadIdx.x;
    const int wave = tid >> 6, lane = tid & 63;

    if (tid < 128) {
        int idx = m0 + tid;
        int s = (idx < cntE) ? slot_list[e * T_TOK + idx] : -1;
        slots_s[tid] = s;
        wgt_s[tid] = (s >= 0) ? slot_w[s] : 0.f;
    }
    __syncthreads();

    // staging: waves 0,1 -> A (gathered h rows); waves 2,3 -> w2 rows.
    const int sub = lane >> 2, kq = lane & 3;
    const unsigned short* gsrc[4];
    unsigned short* ldst[4];
    if (wave < 2) {
#pragma unroll
        for (int i = 0; i < 4; ++i) {
            int row = wave * 64 + i * 16 + sub;
            int slot = slots_s[row];
            int s = (slot >= 0) ? slot : 0;
            gsrc[i] = h_ws + (size_t)s * HID + kq * 8;
            ldst[i] = &As[(wave * 64 + i * 16) * 32];
        }
    } else {
#pragma unroll
        for (int i = 0; i < 4; ++i) {
            int row = (wave - 2) * 64 + i * 16 + sub;
            gsrc[i] = w2b + ((size_t)e * DIM + n0 + row) * HID + kq * 8;
            ldst[i] = &Bs[((wave - 2) * 64 + i * 16) * 32];
        }
    }

    const int wm = wave >> 1, wn = wave & 1;
    const int lrow = lane & 15, koff = (lane >> 4) * 8, quad = lane >> 4;

    f32x4 acc[4][4];
    const f32x4 zf = {0.f, 0.f, 0.f, 0.f};
#pragma unroll
    for (int mi = 0; mi < 4; ++mi)
#pragma unroll
        for (int ni = 0; ni < 4; ++ni) acc[mi][ni] = zf;

    for (int k0 = 0; k0 < HID; k0 += 32) {
#pragma unroll
        for (int i = 0; i < 4; ++i) gl_lds16(gsrc[i], ldst[i]);
#pragma unroll
        for (int i = 0; i < 4; ++i) gsrc[i] += 32;
        __syncthreads();

        bf16x8 af[4], bf[4];
#pragma unroll
        for (int mi = 0; mi < 4; ++mi)
            af[mi] = *(const bf16x8*)&As[(wm * 64 + mi * 16 + lrow) * 32 + koff];
#pragma unroll
        for (int ni = 0; ni < 4; ++ni)
            bf[ni] = *(const bf16x8*)&Bs[(wn * 64 + ni * 16 + lrow) * 32 + koff];
#pragma unroll
        for (int mi = 0; mi < 4; ++mi)
#pragma unroll
            for (int ni = 0; ni < 4; ++ni)
                acc[mi][ni] = __builtin_amdgcn_mfma_f32_16x16x32_bf16(
                    af[mi], bf[ni], acc[mi][ni], 0, 0, 0);
        __syncthreads();
    }

#pragma unroll
    for (int mi = 0; mi < 4; ++mi) {
#pragma unroll
        for (int r = 0; r < 4; ++r) {
            int mloc = wm * 64 + mi * 16 + quad * 4 + r;
            int slot = slots_s[mloc];
            if (slot >= 0) {
                int tok = slot >> 1;
                float w = wgt_s[mloc];
                float* orow = out + (size_t)tok * DIM + n0 + wn * 64 + lrow;
#pragma unroll
                for (int ni = 0; ni < 4; ++ni)
                    atomicAdd(&orow[ni * 16], acc[mi][ni][r] * w);
            }
        }
    }
}

// ---------------------------------------------------------------------------
// Workspace layout (bytes, all 256-aligned):
//   [0, 256)                 cnt[8]                (memset 0 per launch)
//   [256, +262144)           slot_list[8][8192]
//   [+262144, +65536)        slot_w[16384]
//   [327936, +92274688)      h_ws   bf16 [16384][2816]
//   [92602624, +16777216)    x_bf   bf16 [8192][1024]
//   [109379840, +46137344)   w1_bf  bf16 [8][2816][1024]
//   [155517184, +46137344)   w3_bf
//   [201654528, +46137344)   w2_bf  bf16 [8][1024][2816]
//   total ~247.8 MB
// ---------------------------------------------------------------------------
extern "C" void kernel_launch(void* const* d_in, const int* in_sizes, int n_in,
                              void* d_out, int out_size, void* d_ws, size_t ws_size,
                              hipStream_t stream) {
    const float* x  = (const float*)d_in[0];
    const float* gw = (const float*)d_in[1];
    const float* w1 = (const float*)d_in[2];
    const float* w2 = (const float*)d_in[3];
    const float* w3 = (const float*)d_in[4];
    float* out = (float*)d_out;

    char* ws = (char*)d_ws;
    int*   cnt       = (int*)ws;
    int*   slot_list = (int*)(ws + 256);
    float* slot_w    = (float*)(ws + 256 + NEXP * T_TOK * 4);
    unsigned short* h_ws = (unsigned short*)(ws + 327936);
    unsigned short* x_bf = (unsigned short*)(ws + 92602624);
    unsigned short* w1_bf = (unsigned short*)(ws + 109379840);
    unsigned short* w3_bf = (unsigned short*)(ws + 155517184);
    unsigned short* w2_bf = (unsigned short*)(ws + 201654528);

    hipMemsetAsync(cnt, 0, 256, stream);
    hipMemsetAsync(out, 0, (size_t)T_TOK * DIM * sizeof(float), stream);

    const int nx = T_TOK * DIM / 8;              // 1048576
    const int nw = NEXP * HID * DIM / 8;         // 2883584
    cvt_k<<<(nx + 255) / 256, 256, 0, stream>>>(x, x_bf, nx);
    cvt_k<<<(nw + 255) / 256, 256, 0, stream>>>(w1, w1_bf, nw);
    cvt_k<<<(nw + 255) / 256, 256, 0, stream>>>(w3, w3_bf, nw);
    cvt_k<<<(nw + 255) / 256, 256, 0, stream>>>(w2, w2_bf, nw);

    router_k<<<T_TOK / 4, 256, 0, stream>>>(x, gw, cnt, slot_list, slot_w);
    ffn1_k<<<dim3(HID / 64, T_TOK / 128, NEXP), 256, 0, stream>>>(
        x_bf, w1_bf, w3_bf, cnt, slot_list, h_ws);
    ffn2_k<<<dim3(DIM / 128, T_TOK / 128, NEXP), 256, 0, stream>>>(
        h_ws, w2_bf, cnt, slot_list, slot_w, out);
}